// Round 17
// baseline (63.454 us; speedup 1.0000x reference)
//
#include <hip/hip_runtime.h>
#include <math.h>

#define NT 4096
#define EMB 1024
#define DH 64
#define PLANE (NT * DH)          // 262144
#define NSPLIT 16                // attention K-split
#define KPS (NT / NSPLIT)        // 256
#define KVB 128                  // KV tile per iteration (2 iters)
#define KSPLIT 8                 // projection K-split (128 k per block)
#define LOG2E 1.44269504088896f

typedef __attribute__((ext_vector_type(8))) short short8;
typedef __attribute__((ext_vector_type(16))) float f32x16;
typedef unsigned short u16;

union U8 { short8 s; uint4 u; unsigned short h[8]; unsigned int w[4]; };

static __device__ __forceinline__ unsigned short f2bf(float x) {
    union { float f; unsigned int u; } v; v.f = x;
    unsigned int r = v.u + 0x7fffu + ((v.u >> 16) & 1u);
    return (unsigned short)(r >> 16);
}
static __device__ __forceinline__ float bf2f(unsigned short h) {
    union { unsigned int u; float f; } v; v.u = ((unsigned int)h) << 16;
    return v.f;
}
// Hardware packed f32x2 -> bf16x2.
static __device__ __forceinline__ unsigned int cvtpk(float a, float b) {
    unsigned int r;
    asm("v_cvt_pk_bf16_f32 %0, %1, %2" : "=v"(r) : "v"(a), "v"(b));
    return r;
}
// Split pair into hi + compensated lo (self-correcting: lo = cvt(x - hi)).
static __device__ __forceinline__ void split2(float a, float b,
                                              unsigned int& h, unsigned int& lo) {
    h = cvtpk(a, b);
    union { unsigned int u; float f; } ua, ub;
    ua.u = h << 16;
    ub.u = h & 0xffff0000u;
    lo = cvtpk(a - ua.f, b - ub.f);
}

// ---------------------------------------------------------------------------
// Kernel 0: prep W -> transposed split-bf16  WtS[col][k], col in [0,192).
// ---------------------------------------------------------------------------
__global__ __launch_bounds__(256) void prep_w(
    const float* __restrict__ wq, const float* __restrict__ wk,
    const float* __restrict__ wv,
    u16* __restrict__ WtSh, u16* __restrict__ WtSl)
{
    int tid = blockIdx.x * 256 + threadIdx.x;   // 0..24575
    int col = tid >> 7;                          // 0..191
    int ch  = tid & 127;                         // k-chunk of 8
    const float* W = (col < 64) ? wq : (col < 128) ? wk : wv;
    int wcol = col & 63;
    int k0 = ch * 8;
    float x[8];
#pragma unroll
    for (int i = 0; i < 8; ++i) x[i] = W[(size_t)(k0 + i) * DH + wcol];
    uint4 H, L;
    split2(x[0], x[1], H.x, L.x);
    split2(x[2], x[3], H.y, L.y);
    split2(x[4], x[5], H.z, L.z);
    split2(x[6], x[7], H.w, L.w);
    *(uint4*)&WtSh[(size_t)col * EMB + k0] = H;
    *(uint4*)&WtSl[(size_t)col * EMB + k0] = L;
}

// ---------------------------------------------------------------------------
// Kernel 1: MFMA projection — tokens direct-to-register, BK=128 single
// K-step, ONE barrier, uniform 3-pass split (R14-verified body).
// Epilogue: atomicAdd partials into qkvf (f32, zeroed by host memset) —
// kills the 24 MB `part` read-back. grid (32 rb, 2 cb, KSPLIT=8) = 512.
// ---------------------------------------------------------------------------
__global__ __launch_bounds__(256, 2) void proj_mfma(
    const float* __restrict__ tokens,
    const u16* __restrict__ WtSh, const u16* __restrict__ WtSl,
    float* __restrict__ qkvf)
{
    __shared__ u16 Wh[96][128];   // 24 KB, swizzled slots
    __shared__ u16 Wl[96][128];   // 24 KB

    const int t  = threadIdx.x;
    const int rb = blockIdx.x;
    const int cb = blockIdx.y;
    const int ks = blockIdx.z;
    const int w    = t >> 6;
    const int lane = t & 63;
    const int g    = lane >> 5;
    const int c    = lane & 31;
    const int rowbase = rb * 128;
    const int kbase = ks * (EMB / KSPLIT);   // 128-wide K range, single step

    // ---- issue this lane's token loads early (hide under W staging) ----
    const float* trow = tokens + (size_t)(rowbase + w * 32 + c) * EMB + kbase;
    float4 ta[8], tb[8];
#pragma unroll
    for (int kt = 0; kt < 8; ++kt) {
        ta[kt] = *(const float4*)(trow + kt * 16 + g * 8);
        tb[kt] = *(const float4*)(trow + kt * 16 + g * 8 + 4);
    }

    // ---- stage W tile: 96 cols x 128 k, coalesced uint4 copies ----
#pragma unroll
    for (int i = 0; i < 6; ++i) {
        int idx = t + 256 * i;          // 0..1535
        int col = idx >> 4;             // 0..95
        int slot = idx & 15;            // k-chunk of 8 (16 chunks)
        size_t gi = (size_t)(cb * 96 + col) * EMB + kbase + slot * 8;
        int dst = (slot ^ (col & 7)) * 8;
        *(uint4*)&Wh[col][dst] = *(const uint4*)&WtSh[gi];
        *(uint4*)&Wl[col][dst] = *(const uint4*)&WtSl[gi];
    }
    __syncthreads();

    // ---- convert tokens to split-bf16 A-fragments in-register ----
    short8 ah[8], al[8];
#pragma unroll
    for (int kt = 0; kt < 8; ++kt) {
        U8 H, L;
        split2(ta[kt].x, ta[kt].y, H.w[0], L.w[0]);
        split2(ta[kt].z, ta[kt].w, H.w[1], L.w[1]);
        split2(tb[kt].x, tb[kt].y, H.w[2], L.w[2]);
        split2(tb[kt].z, tb[kt].w, H.w[3], L.w[3]);
        ah[kt] = H.s;
        al[kt] = L.s;
    }

    f32x16 acc[3];
#pragma unroll
    for (int ct = 0; ct < 3; ++ct)
#pragma unroll
        for (int i = 0; i < 16; ++i) acc[ct][i] = 0.f;

    // ---- MFMA: 8 kt-substeps of k=16; 3 split passes per col-tile ----
#pragma unroll
    for (int kt = 0; kt < 8; ++kt) {
        int offA = (((kt * 2 + g) ^ (c & 7)) * 8);
#pragma unroll
        for (int ct = 0; ct < 3; ++ct) {
            short8 bh = *(const short8*)&Wh[ct * 32 + c][offA];
            short8 bl = *(const short8*)&Wl[ct * 32 + c][offA];
            acc[ct] = __builtin_amdgcn_mfma_f32_32x32x16_bf16(ah[kt], bh, acc[ct], 0, 0, 0);
            acc[ct] = __builtin_amdgcn_mfma_f32_32x32x16_bf16(ah[kt], bl, acc[ct], 0, 0, 0);
            acc[ct] = __builtin_amdgcn_mfma_f32_32x32x16_bf16(al[kt], bh, acc[ct], 0, 0, 0);
        }
    }

    // ---- epilogue: atomic accumulate into qkvf (coalesced, disjoint) ----
#pragma unroll
    for (int ct = 0; ct < 3; ++ct)
#pragma unroll
        for (int r = 0; r < 16; ++r) {
            int row_l = (r & 3) + 8 * (r >> 2) + 4 * g;
            atomicAdd(&qkvf[(size_t)(rowbase + w * 32 + row_l) * 192 + cb * 96 + ct * 32 + c],
                      acc[ct][r]);
        }
}

// ---------------------------------------------------------------------------
// Kernel 2: convert accumulated qkvf -> attention input formats. K gets
// mask * 0.125 * LOG2E folded in (softmax in base-2). Reads 3 MB (was 24).
// ---------------------------------------------------------------------------
__global__ __launch_bounds__(256) void conv_kernel(
    const float* __restrict__ qkvf, const float* __restrict__ mask,
    u16* __restrict__ Qhg, u16* __restrict__ Qlg,
    u16* __restrict__ Khg, u16* __restrict__ Klg, u16* __restrict__ Vbg)
{
    int tid = blockIdx.x * 256 + threadIdx.x;   // 0..98303
    int row = tid / 24;
    int c8  = tid % 24;
    int colbase = c8 * 8;

    const float* p = qkvf + (size_t)row * 192 + colbase;
    float4 a = *(const float4*)p;
    float4 b = *(const float4*)(p + 4);
    float v[8] = {a.x, a.y, a.z, a.w, b.x, b.y, b.z, b.w};

    int plane = colbase >> 6;      // 0=Q 1=K 2=V
    int pc = colbase & 63;
    size_t o = (size_t)row * DH + pc;
    if (plane == 0) {
        uint4 H, L;
        split2(v[0], v[1], H.x, L.x);
        split2(v[2], v[3], H.y, L.y);
        split2(v[4], v[5], H.z, L.z);
        split2(v[6], v[7], H.w, L.w);
        *(uint4*)&Qhg[o] = H;
        *(uint4*)&Qlg[o] = L;
    } else if (plane == 1) {
        float mk = mask[row] * 0.125f * LOG2E;
        uint4 H, L;
        split2(v[0] * mk, v[1] * mk, H.x, L.x);
        split2(v[2] * mk, v[3] * mk, H.y, L.y);
        split2(v[4] * mk, v[5] * mk, H.z, L.z);
        split2(v[6] * mk, v[7] * mk, H.w, L.w);
        *(uint4*)&Khg[o] = H;
        *(uint4*)&Klg[o] = L;
    } else {
        uint4 H;
        H.x = cvtpk(v[0], v[1]);
        H.y = cvtpk(v[2], v[3]);
        H.z = cvtpk(v[4], v[5]);
        H.w = cvtpk(v[6], v[7]);
        *(uint4*)&Vbg[o] = H;
    }
}

// ---------------------------------------------------------------------------
// Kernel 3: MFMA flash attention, split-bf16 logits, base-2 softmax.
// grid (32, NSPLIT=16) = 512 blocks (2/CU). KVB=128: 2 iterations.
// (R13-verified configuration, unchanged.)
// ---------------------------------------------------------------------------
__global__ __launch_bounds__(256, 2) void attn_mfma(
    const u16* __restrict__ Qhg, const u16* __restrict__ Qlg,
    const u16* __restrict__ Khg, const u16* __restrict__ Klg,
    const u16* __restrict__ Vbg,
    u16* __restrict__ opart, float* __restrict__ mlbuf)
{
    __shared__ u16 Kh[128][64];            // 16 KB
    __shared__ u16 Kl[128][64];            // 16 KB
    __shared__ unsigned int V2[64][64];    // 16 KB (pair-packed rows)

    const int t    = threadIdx.x;
    const int qb   = blockIdx.x;
    const int sp   = blockIdx.y;
    const int wq   = t >> 6;
    const int lane = t & 63;
    const int g    = lane >> 5;
    const int c    = lane & 31;
    const int qrow = qb * 128 + wq * 32 + c;

    // ---- Q fragments (pre-split) ----
    short8 qh[4], ql[4];
#pragma unroll
    for (int kt = 0; kt < 4; ++kt) {
        size_t o = (size_t)qrow * DH + kt * 16 + g * 8;
        U8 H, L;
        H.u = *(const uint4*)&Qhg[o];
        L.u = *(const uint4*)&Qlg[o];
        qh[kt] = H.s;
        ql[kt] = L.s;
    }

    f32x16 oa[2];
#pragma unroll
    for (int i = 0; i < 16; ++i) { oa[0][i] = 0.f; oa[1][i] = 0.f; }
    float m = -INFINITY, l = 0.f;

    for (int cb = 0; cb < KPS / KVB; ++cb) {
        const int kv = sp * KPS + cb * KVB;
        __syncthreads();
        // ---- stage K: 128 rows x 8 slots = 1024 tasks, swizzled ----
#pragma unroll
        for (int it = 0; it < 4; ++it) {
            int idx = it * 256 + t;
            int j = idx >> 3, gr = idx & 7;
            int colp = (gr * 8) ^ ((j & 7) * 8);
            *(uint4*)&Kh[j][colp] = *(const uint4*)&Khg[(size_t)(kv + j) * DH + gr * 8];
            *(uint4*)&Kl[j][colp] = *(const uint4*)&Klg[(size_t)(kv + j) * DH + gr * 8];
        }
        // ---- stage V pair-packed: 64 pair-rows x 8 dgroups = 512 tasks ----
#pragma unroll
        for (int it = 0; it < 2; ++it) {
            int idx = it * 256 + t;
            int a2 = idx >> 3, dg = idx & 7;
            uint4 r0 = *(const uint4*)&Vbg[(size_t)(kv + a2 * 2) * DH + dg * 8];
            uint4 r1 = *(const uint4*)&Vbg[(size_t)(kv + a2 * 2 + 1) * DH + dg * 8];
            const unsigned int* p0 = (const unsigned int*)&r0;
            const unsigned int* p1 = (const unsigned int*)&r1;
            unsigned int wv_[8];
#pragma unroll
            for (int i = 0; i < 4; ++i) {
                wv_[2 * i]     = (p0[i] & 0xFFFFu) | (p1[i] << 16);
                wv_[2 * i + 1] = (p0[i] >> 16)     | (p1[i] & 0xFFFF0000u);
            }
            int colp = (dg * 8) ^ ((a2 & 7) * 8);
            *(uint4*)&V2[a2][colp]     = *(uint4*)&wv_[0];
            *(uint4*)&V2[a2][colp + 4] = *(uint4*)&wv_[4];
        }
        __syncthreads();

        // ---- QK^T: 4 j-tiles of 32, 3 split passes, k = 64 in 4 steps ----
        f32x16 st[4];
#pragma unroll
        for (int jt = 0; jt < 4; ++jt)
#pragma unroll
            for (int i = 0; i < 16; ++i) st[jt][i] = 0.f;
#pragma unroll
        for (int kt = 0; kt < 4; ++kt) {
            int colp = ((kt * 2 + g) * 8) ^ ((c & 7) * 8);
#pragma unroll
            for (int jt = 0; jt < 4; ++jt) {
                short8 kh = *(const short8*)&Kh[jt * 32 + c][colp];
                short8 kl = *(const short8*)&Kl[jt * 32 + c][colp];
                st[jt] = __builtin_amdgcn_mfma_f32_32x32x16_bf16(kh, qh[kt], st[jt], 0, 0, 0);
                st[jt] = __builtin_amdgcn_mfma_f32_32x32x16_bf16(kh, ql[kt], st[jt], 0, 0, 0);
                st[jt] = __builtin_amdgcn_mfma_f32_32x32x16_bf16(kl, qh[kt], st[jt], 0, 0, 0);
            }
        }

        // ---- online softmax over 128 j (base-2) ----
        float p[64];
        float pm = -INFINITY;
#pragma unroll
        for (int jt = 0; jt < 4; ++jt)
#pragma unroll
            for (int r = 0; r < 16; ++r) pm = fmaxf(pm, st[jt][r]);
        pm = fmaxf(pm, __shfl_xor(pm, 32));
        float mn = fmaxf(m, pm);
        float f  = exp2f(m - mn);
        float rs = 0.f;
#pragma unroll
        for (int jt = 0; jt < 4; ++jt)
#pragma unroll
            for (int r = 0; r < 16; ++r) {
                p[jt * 16 + r] = exp2f(st[jt][r] - mn);
                rs += p[jt * 16 + r];
            }
        rs += __shfl_xor(rs, 32);
        l = l * f + rs;
        m = mn;

        // ---- build PA fragments (8 x k=16 chunks over 128 j) ----
        short8 pa[8];
#pragma unroll
        for (int jt = 0; jt < 4; ++jt) {
            const float* pp = &p[jt * 16];
            unsigned int A1 = cvtpk(pp[0], pp[1]),   B1 = cvtpk(pp[4], pp[5]);
            unsigned int A2 = cvtpk(pp[2], pp[3]),   B2 = cvtpk(pp[6], pp[7]);
            unsigned int A3 = cvtpk(pp[8], pp[9]),   B3 = cvtpk(pp[12], pp[13]);
            unsigned int A4 = cvtpk(pp[10], pp[11]), B4 = cvtpk(pp[14], pp[15]);
            unsigned int xA1 = (unsigned int)__shfl_xor((int)A1, 32);
            unsigned int xB1 = (unsigned int)__shfl_xor((int)B1, 32);
            unsigned int xA2 = (unsigned int)__shfl_xor((int)A2, 32);
            unsigned int xB2 = (unsigned int)__shfl_xor((int)B2, 32);
            unsigned int xA3 = (unsigned int)__shfl_xor((int)A3, 32);
            unsigned int xB3 = (unsigned int)__shfl_xor((int)B3, 32);
            unsigned int xA4 = (unsigned int)__shfl_xor((int)A4, 32);
            unsigned int xB4 = (unsigned int)__shfl_xor((int)B4, 32);
            U8 f0, f1;
            f0.w[0] = g ? xB1 : A1;
            f0.w[1] = g ? xB2 : A2;
            f0.w[2] = g ? B1  : xA1;
            f0.w[3] = g ? B2  : xA2;
            f1.w[0] = g ? xB3 : A3;
            f1.w[1] = g ? xB4 : A4;
            f1.w[2] = g ? B3  : xA3;
            f1.w[3] = g ? B4  : xA4;
            pa[jt * 2]     = f0.s;
            pa[jt * 2 + 1] = f1.s;
        }

        // ---- rescale O, then PV (16 MFMA) ----
#pragma unroll
        for (int r = 0; r < 16; ++r) {
            float fr = __shfl(f, (r & 3) + 8 * (r >> 2) + 4 * g);
            oa[0][r] *= fr;
            oa[1][r] *= fr;
        }

#pragma unroll
        for (int dt = 0; dt < 2; ++dt) {
#pragma unroll
            for (int ksl = 0; ksl < 8; ++ksl) {
                U8 bf;
#pragma unroll
                for (int pq = 0; pq < 4; ++pq) {
                    int j2 = ksl * 8 + g * 4 + pq;
                    int col = (dt * 32 + c) ^ ((j2 & 7) * 8);
                    bf.w[pq] = V2[j2][col];
                }
                oa[dt] = __builtin_amdgcn_mfma_f32_32x32x16_bf16(pa[ksl], bf.s, oa[dt], 0, 0, 0);
            }
        }
    }

    // ---- epilogue: normalized O/l as bf16 + (m, l) per row ----
    float inv = 1.f / l;
#pragma unroll
    for (int r = 0; r < 16; ++r) {
        int crow = (r & 3) + 8 * (r >> 2) + 4 * g;
        float li = __shfl(inv, crow);
        int row = qb * 128 + wq * 32 + crow;
        size_t o = ((size_t)sp * NT + row) * DH + c;
        opart[o]      = f2bf(oa[0][r] * li);
        opart[o + 32] = f2bf(oa[1][r] * li);
    }
    if (lane < 32) {
        int row = qb * 128 + wq * 32 + lane;
        mlbuf[((size_t)sp * NT + row) * 2 + 0] = m;
        mlbuf[((size_t)sp * NT + row) * 2 + 1] = l;
    }
}

// ---------------------------------------------------------------------------
// Kernel 4: merge NSPLIT attention partials (bf16, normalized) -> output.
// ---------------------------------------------------------------------------
__global__ __launch_bounds__(256) void merge_kernel(
    const u16* __restrict__ opart, const float* __restrict__ mlbuf,
    float* __restrict__ out)
{
    int idx = (blockIdx.x * 256 + threadIdx.x) * 4;
    int row = idx >> 6;
    int d0  = idx & 63;

    float mv[NSPLIT], lv[NSPLIT];
    float mstar = -INFINITY;
#pragma unroll
    for (int s = 0; s < NSPLIT; ++s) {
        mv[s] = mlbuf[((size_t)s * NT + row) * 2 + 0];
        lv[s] = mlbuf[((size_t)s * NT + row) * 2 + 1];
        mstar = fmaxf(mstar, mv[s]);
    }
    float denom = 0.f;
    float ax = 0.f, ay = 0.f, az = 0.f, aw = 0.f;
#pragma unroll
    for (int s = 0; s < NSPLIT; ++s) {
        float w = lv[s] * exp2f(mv[s] - mstar);
        denom += w;
        uint2 ov = *(const uint2*)&opart[((size_t)s * NT + row) * DH + d0];
        ax += w * bf2f((u16)(ov.x & 0xFFFFu));
        ay += w * bf2f((u16)(ov.x >> 16));
        az += w * bf2f((u16)(ov.y & 0xFFFFu));
        aw += w * bf2f((u16)(ov.y >> 16));
    }
    float inv = 1.f / denom;
    *(float4*)&out[idx] = make_float4(ax * inv, ay * inv, az * inv, aw * inv);
}

// ---------------------------------------------------------------------------
extern "C" void kernel_launch(void* const* d_in, const int* in_sizes, int n_in,
                              void* d_out, int out_size, void* d_ws, size_t ws_size,
                              hipStream_t stream) {
    const float* tokens = (const float*)d_in[0];
    const float* mask   = (const float*)d_in[1];
    const float* wq     = (const float*)d_in[2];
    const float* wk     = (const float*)d_in[3];
    const float* wv     = (const float*)d_in[4];
    char*  wsb = (char*)d_ws;
    float* out = (float*)d_out;

    u16* WtSh = (u16*)wsb;                                   // 0 .. 384K
    u16* WtSl = WtSh + 192 * EMB;                            // 384K .. 768K
    u16* Qhg  = WtSl + 192 * EMB;                            // 768K ..
    u16* Qlg  = Qhg + PLANE;
    u16* Khg  = Qlg + PLANE;
    u16* Klg  = Khg + PLANE;
    u16* Vbg  = Klg + PLANE;                                 // ends ~3.3M
    u16*   opart = (u16*)(wsb + (size_t)4 * 1024 * 1024);    // 4M..12M (8 MB bf16)
    float* mlbuf = (float*)(wsb + (size_t)16 * 1024 * 1024); // 512K
    float* qkvf  = (float*)(wsb + (size_t)20 * 1024 * 1024); // 3 MB f32 accumulator

    hipMemsetAsync(qkvf, 0, (size_t)NT * 192 * sizeof(float), stream);
    hipLaunchKernelGGL(prep_w, dim3(96), dim3(256), 0, stream,
                       wq, wk, wv, WtSh, WtSl);
    hipLaunchKernelGGL(proj_mfma, dim3(32, 2, KSPLIT), dim3(256), 0, stream,
                       tokens, WtSh, WtSl, qkvf);
    hipLaunchKernelGGL(conv_kernel, dim3(384), dim3(256), 0, stream,
                       qkvf, mask, Qhg, Qlg, Khg, Klg, Vbg);
    hipLaunchKernelGGL(attn_mfma, dim3(NT / 128, NSPLIT), dim3(256), 0, stream,
                       Qhg, Qlg, Khg, Klg, Vbg, opart, mlbuf);
    hipLaunchKernelGGL(merge_kernel, dim3(256), dim3(256), 0, stream,
                       opart, mlbuf, out);
}

// Round 18
// 48.073 us; speedup vs baseline: 1.3200x; 1.3200x over previous
//
#include <hip/hip_runtime.h>
#include <math.h>

#define NT 4096
#define EMB 1024
#define DH 64
#define PLANE (NT * DH)          // 262144
#define NSPLIT 16                // attention K-split
#define KPS (NT / NSPLIT)        // 256
#define KVB 128                  // KV tile per iteration (2 iters)
#define KSPLIT 8                 // projection K-split
#define LOG2E 1.44269504088896f

typedef __attribute__((ext_vector_type(8))) short short8;
typedef __attribute__((ext_vector_type(16))) float f32x16;
typedef unsigned short u16;

union U8 { short8 s; uint4 u; unsigned short h[8]; unsigned int w[4]; };

static __device__ __forceinline__ unsigned short f2bf(float x) {
    union { float f; unsigned int u; } v; v.f = x;
    unsigned int r = v.u + 0x7fffu + ((v.u >> 16) & 1u);
    return (unsigned short)(r >> 16);
}
static __device__ __forceinline__ float bf2f(unsigned short h) {
    union { unsigned int u; float f; } v; v.u = ((unsigned int)h) << 16;
    return v.f;
}
// Hardware packed f32x2 -> bf16x2.
static __device__ __forceinline__ unsigned int cvtpk(float a, float b) {
    unsigned int r;
    asm("v_cvt_pk_bf16_f32 %0, %1, %2" : "=v"(r) : "v"(a), "v"(b));
    return r;
}
// Split pair into hi + compensated lo (self-correcting: lo = cvt(x - hi)).
static __device__ __forceinline__ void split2(float a, float b,
                                              unsigned int& h, unsigned int& lo) {
    h = cvtpk(a, b);
    union { unsigned int u; float f; } ua, ub;
    ua.u = h << 16;
    ub.u = h & 0xffff0000u;
    lo = cvtpk(a - ua.f, b - ub.f);
}

// ---------------------------------------------------------------------------
// Kernel 1: MFMA projection, inline token AND W split (native cvt), K-split.
// grid (32 rowblocks, 2 colblocks, KSPLIT=8) = 512 blocks (2/CU). 4 waves.
// (R13-verified 48.9us configuration.)
// ---------------------------------------------------------------------------
__global__ __launch_bounds__(256) void proj_mfma(
    const float* __restrict__ tokens,
    const float* __restrict__ wq, const float* __restrict__ wk,
    const float* __restrict__ wv,
    float* __restrict__ part)
{
    __shared__ u16 Th[128][64];   // 16 KB, swizzled slots
    __shared__ u16 Tl[128][64];
    __shared__ u16 Wh[96][64];
    __shared__ u16 Wl[96][64];

    const int t  = threadIdx.x;
    const int rb = blockIdx.x;
    const int cb = blockIdx.y;
    const int ks = blockIdx.z;
    const int w    = t >> 6;
    const int lane = t & 63;
    const int g    = lane >> 5;
    const int c    = lane & 31;
    const int rowbase = rb * 128;

    f32x16 acc[3];
#pragma unroll
    for (int ct = 0; ct < 3; ++ct)
#pragma unroll
        for (int i = 0; i < 16; ++i) acc[ct][i] = 0.f;

    for (int st = 0; st < 2; ++st) {
        const int kbase = ks * (EMB / KSPLIT) + st * 64;
        __syncthreads();
        // ---- stage tokens: 128 rows x 64 k, f32 -> split bf16 (cvt_pk) ----
#pragma unroll
        for (int i = 0; i < 4; ++i) {
            int idx = t + 256 * i;          // 0..1023
            int r = idx >> 3;               // 0..127
            int slot = idx & 7;
            const float* gp = tokens + (size_t)(rowbase + r) * EMB + kbase + slot * 8;
            float4 a = *(const float4*)gp;
            float4 b = *(const float4*)(gp + 4);
            uint4 H, L;
            split2(a.x, a.y, H.x, L.x);
            split2(a.z, a.w, H.y, L.y);
            split2(b.x, b.y, H.z, L.z);
            split2(b.z, b.w, H.w, L.w);
            int dst = (slot ^ (r & 7)) * 8;
            *(uint4*)&Th[r][dst] = H;
            *(uint4*)&Tl[r][dst] = L;
        }
        // ---- stage W: 96 cols x 64 k, inline transpose+split from f32 ----
#pragma unroll
        for (int i = 0; i < 3; ++i) {
            int idx = t + 256 * i;          // 0..767
            int col = idx >> 3;             // 0..95
            int slot = idx & 7;
            int colg = cb * 96 + col;
            const float* W = (colg < 64) ? wq : (colg < 128) ? wk : wv;
            const float* wp = W + (size_t)(kbase + slot * 8) * DH + (colg & 63);
            float x[8];
#pragma unroll
            for (int j = 0; j < 8; ++j) x[j] = wp[j * DH];
            uint4 H, L;
            split2(x[0], x[1], H.x, L.x);
            split2(x[2], x[3], H.y, L.y);
            split2(x[4], x[5], H.z, L.z);
            split2(x[6], x[7], H.w, L.w);
            int dst = (slot ^ (col & 7)) * 8;
            *(uint4*)&Wh[col][dst] = H;
            *(uint4*)&Wl[col][dst] = L;
        }
        __syncthreads();

        // ---- MFMA: 4 kt-substeps of k=16; 3 split passes per col-tile ----
#pragma unroll
        for (int kt = 0; kt < 4; ++kt) {
            int sA = kt * 2 + g;
            int offA = ((sA ^ (c & 7)) * 8);
            short8 ah = *(const short8*)&Th[w * 32 + c][offA];
            short8 al = *(const short8*)&Tl[w * 32 + c][offA];
#pragma unroll
            for (int ct = 0; ct < 3; ++ct) {
                short8 bh = *(const short8*)&Wh[ct * 32 + c][offA];
                short8 bl = *(const short8*)&Wl[ct * 32 + c][offA];
                acc[ct] = __builtin_amdgcn_mfma_f32_32x32x16_bf16(ah, bh, acc[ct], 0, 0, 0);
                acc[ct] = __builtin_amdgcn_mfma_f32_32x32x16_bf16(ah, bl, acc[ct], 0, 0, 0);
                acc[ct] = __builtin_amdgcn_mfma_f32_32x32x16_bf16(al, bh, acc[ct], 0, 0, 0);
            }
        }
    }

    // ---- epilogue: partial f32 ----
#pragma unroll
    for (int ct = 0; ct < 3; ++ct)
#pragma unroll
        for (int r = 0; r < 16; ++r) {
            int row_l = (r & 3) + 8 * (r >> 2) + 4 * g;
            part[((size_t)ks * NT + rowbase + w * 32 + row_l) * 192 + cb * 96 + ct * 32 + c]
                = acc[ct][r];
        }
}

// ---------------------------------------------------------------------------
// Kernel 2: merge KSPLIT partials + convert (native cvt). K gets
// mask * 0.125 * LOG2E folded in (softmax in base-2).
// ---------------------------------------------------------------------------
__global__ __launch_bounds__(256) void merge_conv(
    const float* __restrict__ part, const float* __restrict__ mask,
    u16* __restrict__ Qhg, u16* __restrict__ Qlg,
    u16* __restrict__ Khg, u16* __restrict__ Klg, u16* __restrict__ Vbg)
{
    int tid = blockIdx.x * 256 + threadIdx.x;   // 0..98303
    int row = tid / 24;
    int c8  = tid % 24;
    int colbase = c8 * 8;

    float v[8];
#pragma unroll
    for (int i = 0; i < 8; ++i) v[i] = 0.f;
#pragma unroll
    for (int s = 0; s < KSPLIT; ++s) {
        const float* p = part + ((size_t)s * NT + row) * 192 + colbase;
        float4 a = *(const float4*)p;
        float4 b = *(const float4*)(p + 4);
        v[0] += a.x; v[1] += a.y; v[2] += a.z; v[3] += a.w;
        v[4] += b.x; v[5] += b.y; v[6] += b.z; v[7] += b.w;
    }

    int plane = colbase >> 6;      // 0=Q 1=K 2=V
    int pc = colbase & 63;
    size_t o = (size_t)row * DH + pc;
    if (plane == 0) {
        uint4 H, L;
        split2(v[0], v[1], H.x, L.x);
        split2(v[2], v[3], H.y, L.y);
        split2(v[4], v[5], H.z, L.z);
        split2(v[6], v[7], H.w, L.w);
        *(uint4*)&Qhg[o] = H;
        *(uint4*)&Qlg[o] = L;
    } else if (plane == 1) {
        float mk = mask[row] * 0.125f * LOG2E;
        uint4 H, L;
        split2(v[0] * mk, v[1] * mk, H.x, L.x);
        split2(v[2] * mk, v[3] * mk, H.y, L.y);
        split2(v[4] * mk, v[5] * mk, H.z, L.z);
        split2(v[6] * mk, v[7] * mk, H.w, L.w);
        *(uint4*)&Khg[o] = H;
        *(uint4*)&Klg[o] = L;
    } else {
        uint4 H;
        H.x = cvtpk(v[0], v[1]);
        H.y = cvtpk(v[2], v[3]);
        H.z = cvtpk(v[4], v[5]);
        H.w = cvtpk(v[6], v[7]);
        *(uint4*)&Vbg[o] = H;
    }
}

// ---------------------------------------------------------------------------
// Kernel 3: MFMA flash attention, split-bf16 logits, base-2 softmax.
// grid (32, NSPLIT=16) = 512 blocks (2/CU). KVB=128: 2 iterations, 4
// barriers total. Stores normalized O/l as bf16.
// ---------------------------------------------------------------------------
__global__ __launch_bounds__(256, 2) void attn_mfma(
    const u16* __restrict__ Qhg, const u16* __restrict__ Qlg,
    const u16* __restrict__ Khg, const u16* __restrict__ Klg,
    const u16* __restrict__ Vbg,
    u16* __restrict__ opart, float* __restrict__ mlbuf)
{
    __shared__ u16 Kh[128][64];            // 16 KB
    __shared__ u16 Kl[128][64];            // 16 KB
    __shared__ unsigned int V2[64][64];    // 16 KB (pair-packed rows)

    const int t    = threadIdx.x;
    const int qb   = blockIdx.x;
    const int sp   = blockIdx.y;
    const int wq   = t >> 6;
    const int lane = t & 63;
    const int g    = lane >> 5;
    const int c    = lane & 31;
    const int qrow = qb * 128 + wq * 32 + c;

    // ---- Q fragments (pre-split) ----
    short8 qh[4], ql[4];
#pragma unroll
    for (int kt = 0; kt < 4; ++kt) {
        size_t o = (size_t)qrow * DH + kt * 16 + g * 8;
        U8 H, L;
        H.u = *(const uint4*)&Qhg[o];
        L.u = *(const uint4*)&Qlg[o];
        qh[kt] = H.s;
        ql[kt] = L.s;
    }

    f32x16 oa[2];
#pragma unroll
    for (int i = 0; i < 16; ++i) { oa[0][i] = 0.f; oa[1][i] = 0.f; }
    float m = -INFINITY, l = 0.f;

    for (int cb = 0; cb < KPS / KVB; ++cb) {
        const int kv = sp * KPS + cb * KVB;
        __syncthreads();
        // ---- stage K: 128 rows x 8 slots = 1024 tasks, swizzled ----
#pragma unroll
        for (int it = 0; it < 4; ++it) {
            int idx = it * 256 + t;
            int j = idx >> 3, gr = idx & 7;
            int colp = (gr * 8) ^ ((j & 7) * 8);
            *(uint4*)&Kh[j][colp] = *(const uint4*)&Khg[(size_t)(kv + j) * DH + gr * 8];
            *(uint4*)&Kl[j][colp] = *(const uint4*)&Klg[(size_t)(kv + j) * DH + gr * 8];
        }
        // ---- stage V pair-packed: 64 pair-rows x 8 dgroups = 512 tasks ----
#pragma unroll
        for (int it = 0; it < 2; ++it) {
            int idx = it * 256 + t;
            int a2 = idx >> 3, dg = idx & 7;
            uint4 r0 = *(const uint4*)&Vbg[(size_t)(kv + a2 * 2) * DH + dg * 8];
            uint4 r1 = *(const uint4*)&Vbg[(size_t)(kv + a2 * 2 + 1) * DH + dg * 8];
            const unsigned int* p0 = (const unsigned int*)&r0;
            const unsigned int* p1 = (const unsigned int*)&r1;
            unsigned int wv_[8];
#pragma unroll
            for (int i = 0; i < 4; ++i) {
                wv_[2 * i]     = (p0[i] & 0xFFFFu) | (p1[i] << 16);
                wv_[2 * i + 1] = (p0[i] >> 16)     | (p1[i] & 0xFFFF0000u);
            }
            int colp = (dg * 8) ^ ((a2 & 7) * 8);
            *(uint4*)&V2[a2][colp]     = *(uint4*)&wv_[0];
            *(uint4*)&V2[a2][colp + 4] = *(uint4*)&wv_[4];
        }
        __syncthreads();

        // ---- QK^T: 4 j-tiles of 32, 3 split passes, k = 64 in 4 steps ----
        f32x16 st[4];
#pragma unroll
        for (int jt = 0; jt < 4; ++jt)
#pragma unroll
            for (int i = 0; i < 16; ++i) st[jt][i] = 0.f;
#pragma unroll
        for (int kt = 0; kt < 4; ++kt) {
            int colp = ((kt * 2 + g) * 8) ^ ((c & 7) * 8);
#pragma unroll
            for (int jt = 0; jt < 4; ++jt) {
                short8 kh = *(const short8*)&Kh[jt * 32 + c][colp];
                short8 kl = *(const short8*)&Kl[jt * 32 + c][colp];
                st[jt] = __builtin_amdgcn_mfma_f32_32x32x16_bf16(kh, qh[kt], st[jt], 0, 0, 0);
                st[jt] = __builtin_amdgcn_mfma_f32_32x32x16_bf16(kh, ql[kt], st[jt], 0, 0, 0);
                st[jt] = __builtin_amdgcn_mfma_f32_32x32x16_bf16(kl, qh[kt], st[jt], 0, 0, 0);
            }
        }

        // ---- online softmax over 128 j (base-2) ----
        float p[64];
        float pm = -INFINITY;
#pragma unroll
        for (int jt = 0; jt < 4; ++jt)
#pragma unroll
            for (int r = 0; r < 16; ++r) pm = fmaxf(pm, st[jt][r]);
        pm = fmaxf(pm, __shfl_xor(pm, 32));
        float mn = fmaxf(m, pm);
        float f  = exp2f(m - mn);
        float rs = 0.f;
#pragma unroll
        for (int jt = 0; jt < 4; ++jt)
#pragma unroll
            for (int r = 0; r < 16; ++r) {
                p[jt * 16 + r] = exp2f(st[jt][r] - mn);
                rs += p[jt * 16 + r];
            }
        rs += __shfl_xor(rs, 32);
        l = l * f + rs;
        m = mn;

        // ---- build PA fragments (8 x k=16 chunks over 128 j) ----
        short8 pa[8];
#pragma unroll
        for (int jt = 0; jt < 4; ++jt) {
            const float* pp = &p[jt * 16];
            unsigned int A1 = cvtpk(pp[0], pp[1]),   B1 = cvtpk(pp[4], pp[5]);
            unsigned int A2 = cvtpk(pp[2], pp[3]),   B2 = cvtpk(pp[6], pp[7]);
            unsigned int A3 = cvtpk(pp[8], pp[9]),   B3 = cvtpk(pp[12], pp[13]);
            unsigned int A4 = cvtpk(pp[10], pp[11]), B4 = cvtpk(pp[14], pp[15]);
            unsigned int xA1 = (unsigned int)__shfl_xor((int)A1, 32);
            unsigned int xB1 = (unsigned int)__shfl_xor((int)B1, 32);
            unsigned int xA2 = (unsigned int)__shfl_xor((int)A2, 32);
            unsigned int xB2 = (unsigned int)__shfl_xor((int)B2, 32);
            unsigned int xA3 = (unsigned int)__shfl_xor((int)A3, 32);
            unsigned int xB3 = (unsigned int)__shfl_xor((int)B3, 32);
            unsigned int xA4 = (unsigned int)__shfl_xor((int)A4, 32);
            unsigned int xB4 = (unsigned int)__shfl_xor((int)B4, 32);
            U8 f0, f1;
            f0.w[0] = g ? xB1 : A1;
            f0.w[1] = g ? xB2 : A2;
            f0.w[2] = g ? B1  : xA1;
            f0.w[3] = g ? B2  : xA2;
            f1.w[0] = g ? xB3 : A3;
            f1.w[1] = g ? xB4 : A4;
            f1.w[2] = g ? B3  : xA3;
            f1.w[3] = g ? B4  : xA4;
            pa[jt * 2]     = f0.s;
            pa[jt * 2 + 1] = f1.s;
        }

        // ---- rescale O, then PV (16 MFMA) ----
#pragma unroll
        for (int r = 0; r < 16; ++r) {
            float fr = __shfl(f, (r & 3) + 8 * (r >> 2) + 4 * g);
            oa[0][r] *= fr;
            oa[1][r] *= fr;
        }

#pragma unroll
        for (int dt = 0; dt < 2; ++dt) {
#pragma unroll
            for (int ksl = 0; ksl < 8; ++ksl) {
                U8 bf;
#pragma unroll
                for (int pq = 0; pq < 4; ++pq) {
                    int j2 = ksl * 8 + g * 4 + pq;
                    int col = (dt * 32 + c) ^ ((j2 & 7) * 8);
                    bf.w[pq] = V2[j2][col];
                }
                oa[dt] = __builtin_amdgcn_mfma_f32_32x32x16_bf16(pa[ksl], bf.s, oa[dt], 0, 0, 0);
            }
        }
    }

    // ---- epilogue: normalized O/l as bf16 + (m, l) per row ----
    float inv = 1.f / l;
#pragma unroll
    for (int r = 0; r < 16; ++r) {
        int crow = (r & 3) + 8 * (r >> 2) + 4 * g;
        float li = __shfl(inv, crow);
        int row = qb * 128 + wq * 32 + crow;
        size_t o = ((size_t)sp * NT + row) * DH + c;
        opart[o]      = f2bf(oa[0][r] * li);
        opart[o + 32] = f2bf(oa[1][r] * li);
    }
    if (lane < 32) {
        int row = qb * 128 + wq * 32 + lane;
        mlbuf[((size_t)sp * NT + row) * 2 + 0] = m;
        mlbuf[((size_t)sp * NT + row) * 2 + 1] = l;
    }
}

// ---------------------------------------------------------------------------
// Kernel 4: merge NSPLIT attention partials (bf16, normalized) -> output.
// ---------------------------------------------------------------------------
__global__ __launch_bounds__(256) void merge_kernel(
    const u16* __restrict__ opart, const float* __restrict__ mlbuf,
    float* __restrict__ out)
{
    int idx = (blockIdx.x * 256 + threadIdx.x) * 4;
    int row = idx >> 6;
    int d0  = idx & 63;

    float mv[NSPLIT], lv[NSPLIT];
    float mstar = -INFINITY;
#pragma unroll
    for (int s = 0; s < NSPLIT; ++s) {
        mv[s] = mlbuf[((size_t)s * NT + row) * 2 + 0];
        lv[s] = mlbuf[((size_t)s * NT + row) * 2 + 1];
        mstar = fmaxf(mstar, mv[s]);
    }
    float denom = 0.f;
    float ax = 0.f, ay = 0.f, az = 0.f, aw = 0.f;
#pragma unroll
    for (int s = 0; s < NSPLIT; ++s) {
        float w = lv[s] * exp2f(mv[s] - mstar);
        denom += w;
        uint2 ov = *(const uint2*)&opart[((size_t)s * NT + row) * DH + d0];
        ax += w * bf2f((u16)(ov.x & 0xFFFFu));
        ay += w * bf2f((u16)(ov.x >> 16));
        az += w * bf2f((u16)(ov.y & 0xFFFFu));
        aw += w * bf2f((u16)(ov.y >> 16));
    }
    float inv = 1.f / denom;
    *(float4*)&out[idx] = make_float4(ax * inv, ay * inv, az * inv, aw * inv);
}

// ---------------------------------------------------------------------------
extern "C" void kernel_launch(void* const* d_in, const int* in_sizes, int n_in,
                              void* d_out, int out_size, void* d_ws, size_t ws_size,
                              hipStream_t stream) {
    const float* tokens = (const float*)d_in[0];
    const float* mask   = (const float*)d_in[1];
    const float* wq     = (const float*)d_in[2];
    const float* wk     = (const float*)d_in[3];
    const float* wv     = (const float*)d_in[4];
    char*  wsb = (char*)d_ws;
    float* out = (float*)d_out;

    u16* Qhg  = (u16*)wsb;                                   // 5 planes x 512 KB
    u16* Qlg  = Qhg + PLANE;
    u16* Khg  = Qlg + PLANE;
    u16* Klg  = Khg + PLANE;
    u16* Vbg  = Klg + PLANE;                                 // ends ~2.5M
    float* part  = (float*)(wsb + (size_t)4 * 1024 * 1024);  // 4M .. 28M (KSPLIT f32)
    u16*   opart = (u16*)(wsb + (size_t)4 * 1024 * 1024);    // reuse: 8 MB bf16
    float* mlbuf = (float*)(wsb + (size_t)28 * 1024 * 1024); // 512K

    hipLaunchKernelGGL(proj_mfma, dim3(32, 2, KSPLIT), dim3(256), 0, stream,
                       tokens, wq, wk, wv, part);
    hipLaunchKernelGGL(merge_conv, dim3(384), dim3(256), 0, stream,
                       part, mask, Qhg, Qlg, Khg, Klg, Vbg);
    hipLaunchKernelGGL(attn_mfma, dim3(NT / 128, NSPLIT), dim3(256), 0, stream,
                       Qhg, Qlg, Khg, Klg, Vbg, opart, mlbuf);
    hipLaunchKernelGGL(merge_kernel, dim3(256), dim3(256), 0, stream,
                       opart, mlbuf, out);
}